// Round 7
// baseline (121.054 us; speedup 1.0000x reference)
//
#include <hip/hip_runtime.h>
#include <hip/hip_bf16.h>
#include <stdint.h>

typedef __bf16 bf16;
typedef __attribute__((ext_vector_type(8))) __bf16 bf16x8;
typedef __attribute__((ext_vector_type(4))) float f32x4;
typedef __attribute__((ext_vector_type(16))) float f32x16;

#define L2E 1.4426950408889634f

__device__ __forceinline__ f32x4 mfma16(bf16x8 a, bf16x8 b, f32x4 c) {
  return __builtin_amdgcn_mfma_f32_16x16x32_bf16(a, b, c, 0, 0, 0);
}

__device__ __forceinline__ f32x16 mfma32(bf16x8 a, bf16x8 b, f32x16 c) {
  return __builtin_amdgcn_mfma_f32_32x32x16_bf16(a, b, c, 0, 0, 0);
}

__device__ __forceinline__ void gload16(void* lds, const void* g) {
  __builtin_amdgcn_global_load_lds(
      (const __attribute__((address_space(1))) uint32_t*)g,
      (__attribute__((address_space(3))) uint32_t*)lds, 16, 0, 0);
}

__device__ __forceinline__ unsigned cvt_pk_bf16(float lo, float hi) {
  unsigned r;
  asm("v_cvt_pk_bf16_f32 %0, %1, %2" : "=v"(r) : "v"(lo), "v"(hi));
  return r;
}

// v_permlane32_swap_b32: a' = [a_lo | b_lo], b' = [a_hi | b_hi]
__device__ __forceinline__ void pl32swap(unsigned& a, unsigned& b) {
  auto r = __builtin_amdgcn_permlane32_swap(a, b, false, false);
  a = r[0];
  b = r[1];
}

// ---------------- prep: fp32 -> bf16 ----------------
__global__ __launch_bounds__(256) void prep_cast(
    const float* __restrict__ x, const float* __restrict__ wq,
    const float* __restrict__ wk, const float* __restrict__ wv,
    const float* __restrict__ wo, bf16* __restrict__ xb,
    bf16* __restrict__ wqb, bf16* __restrict__ wkb, bf16* __restrict__ wvb,
    bf16* __restrict__ wob) {
  int i = blockIdx.x * 256 + threadIdx.x;  // unit of 4 floats
  const int NX = 4096 * 1024 / 4;
  const int NW = 1024 * 1024 / 4;
  const float* src; bf16* dst; int off;
  if (i < NX)               { src = x;  dst = xb;  off = i; }
  else if (i < NX + NW)     { src = wq; dst = wqb; off = i - NX; }
  else if (i < NX + 2 * NW) { src = wk; dst = wkb; off = i - (NX + NW); }
  else if (i < NX + 3 * NW) { src = wv; dst = wvb; off = i - (NX + 2 * NW); }
  else                      { src = wo; dst = wob; off = i - (NX + 3 * NW); }
  float4 v = ((const float4*)src)[off];
  union { bf16 h[4]; uint2 u; } o;
  o.h[0] = (bf16)v.x; o.h[1] = (bf16)v.y; o.h[2] = (bf16)v.z; o.h[3] = (bf16)v.w;
  ((uint2*)dst)[off] = o.u;
}

// ---------------- RoPE tables: [2048][32] fp32 ----------------
__global__ __launch_bounds__(256) void rope_tab(float* __restrict__ ct,
                                                float* __restrict__ st) {
  int i = blockIdx.x * 256 + threadIdx.x;  // 65536
  int t = i >> 5, d = i & 31;
  float inv = powf(10000.f, -(float)d * (1.f / 32.f));
  float a = (float)t * inv;
  ct[i] = cosf(a);
  st[i] = sinf(a);
}

// ---------------- shared GEMM mainloop: C = A[4096x1024] * W^T[1024x1024] tile
// 128x128 tile, BK=32, 4 waves 2x2, double-buffered LDS, swizzled (rule #21)
__device__ __forceinline__ void gemm_mainloop(const bf16* __restrict__ A,
                                              const bf16* __restrict__ W,
                                              int m0, int n0,
                                              bf16 (*As)[4096], bf16 (*Bs)[4096],
                                              f32x4 acc[4][4]) {
  const int tid = threadIdx.x;
  const int lane = tid & 63, wave = tid >> 6;
  const int wr = (wave >> 1) * 64, wc = (wave & 1) * 64;
  const int lr = lane & 15, lh = lane >> 4;

  auto stage = [&](bf16* dA, bf16* dB, int kt) {
    int k0 = kt * 32;
#pragma unroll
    for (int p = 0; p < 2; p++) {
      int u = p * 256 + tid; int row = u >> 2; int kg = (u & 3) ^ (row & 3);
      gload16(dA + (size_t)u * 8, A + (size_t)(m0 + row) * 1024 + k0 + kg * 8);
    }
#pragma unroll
    for (int p = 0; p < 2; p++) {
      int u = p * 256 + tid; int row = u >> 2; int kg = (u & 3) ^ (row & 3);
      gload16(dB + (size_t)u * 8, W + (size_t)(n0 + row) * 1024 + k0 + kg * 8);
    }
  };

  stage(As[0], Bs[0], 0);
  int cur = 0;
  for (int kt = 0; kt < 32; ++kt) {
    __syncthreads();
    const bf16* cA = As[cur]; const bf16* cB = Bs[cur];
    bf16x8 af[4], bfr[4];
#pragma unroll
    for (int i = 0; i < 4; i++) {
      int row = wr + i * 16 + lr; int un = row * 4 + (lh ^ (row & 3));
      af[i] = *(const bf16x8*)(cA + (size_t)un * 8);
    }
#pragma unroll
    for (int j = 0; j < 4; j++) {
      int row = wc + j * 16 + lr; int un = row * 4 + (lh ^ (row & 3));
      bfr[j] = *(const bf16x8*)(cB + (size_t)un * 8);
    }
    if (kt + 1 < 32) stage(As[cur ^ 1], Bs[cur ^ 1], kt + 1);
#pragma unroll
    for (int i = 0; i < 4; i++)
#pragma unroll
      for (int j = 0; j < 4; j++) acc[i][j] = mfma16(af[i], bfr[j], acc[i][j]);
    cur ^= 1;
  }
}

// ---------------- QKV projection + RoPE epilogue ----------------
// out layouts: q/k/v [32 bh][2048 t][64 d] bf16; q pre-scaled by 0.125*log2(e)
__global__ __launch_bounds__(256) void gemm_qkv(
    const bf16* __restrict__ xb, const bf16* __restrict__ wq,
    const bf16* __restrict__ wk, const bf16* __restrict__ wv,
    const float* __restrict__ ct, const float* __restrict__ st,
    bf16* __restrict__ qo, bf16* __restrict__ ko, bf16* __restrict__ vo) {
  __shared__ __align__(16) bf16 As[2][4096];
  __shared__ __align__(16) bf16 Bs[2][4096];
  int bm = blockIdx.x, bn = blockIdx.y;
  int proj = bn >> 3;
  const bf16* W = proj == 0 ? wq : (proj == 1 ? wk : wv);
  bf16* out = proj == 0 ? qo : (proj == 1 ? ko : vo);
  int m0 = bm * 128, n0 = (bn & 7) * 128;

  f32x4 zero = {0.f, 0.f, 0.f, 0.f};
  f32x4 acc[4][4];
#pragma unroll
  for (int i = 0; i < 4; i++)
#pragma unroll
    for (int j = 0; j < 4; j++) acc[i][j] = zero;

  gemm_mainloop(xb, W, m0, n0, As, Bs, acc);

  const int tid = threadIdx.x, lane = tid & 63, wave = tid >> 6;
  const int wr = (wave >> 1) * 64, wc = (wave & 1) * 64;
  const int lr = lane & 15, lh = lane >> 4;
  int colb = n0 + wc;          // multiple of 64 -> single head per wave window
  int h = colb >> 6;
  const float QSC = 0.125f * L2E;  // fold softmax scale and log2(e) into Q
#pragma unroll
  for (int i = 0; i < 4; i++) {
#pragma unroll
    for (int r = 0; r < 4; r++) {
      int m = m0 + wr + i * 16 + lh * 4 + r;
      int b = m >> 11, t = m & 2047;
      float v0 = acc[i][0][r], v1 = acc[i][1][r];
      float v2 = acc[i][2][r], v3 = acc[i][3][r];
      if (proj < 2) {  // RoPE: pairs (d, d+32) are frags (0,2) and (1,3)
        float c0 = ct[t * 32 + lr],      s0 = st[t * 32 + lr];
        float c1 = ct[t * 32 + 16 + lr], s1 = st[t * 32 + 16 + lr];
        float n0v = v0 * c0 - v2 * s0, n2 = v2 * c0 + v0 * s0;
        float n1 = v1 * c1 - v3 * s1,  n3 = v3 * c1 + v1 * s1;
        v0 = n0v; v1 = n1; v2 = n2; v3 = n3;
        if (proj == 0) { v0 *= QSC; v1 *= QSC; v2 *= QSC; v3 *= QSC; }
      }
      size_t base = ((size_t)(b * 16 + h) * 2048 + t) * 64;
      out[base + lr]      = (bf16)v0;
      out[base + 16 + lr] = (bf16)v1;
      out[base + 32 + lr] = (bf16)v2;
      out[base + 48 + lr] = (bf16)v3;
    }
  }
}

// ---------------- V transpose: [bh][t][d] -> [bh][d][t] ----------------
__global__ __launch_bounds__(256) void vtrans(const bf16* __restrict__ v,
                                              bf16* __restrict__ vt) {
  __shared__ bf16 tile[64][68];
  int bh = blockIdx.x, tt = blockIdx.y;
  int tid = threadIdx.x;
  const bf16* src = v + ((size_t)bh * 2048 + tt * 64) * 64;
  int rr0 = tid >> 4;
  int c4 = (tid & 15) * 4;
#pragma unroll
  for (int p = 0; p < 4; p++) {
    int r = p * 16 + rr0;
    *(uint2*)&tile[r][c4] = *(const uint2*)(src + (size_t)r * 64 + c4);
  }
  __syncthreads();
  bf16* dst = vt + (size_t)bh * 64 * 2048 + tt * 64;
#pragma unroll
  for (int p = 0; p < 4; p++) {
    int d = p * 16 + rr0;
    union { bf16 h[4]; uint2 u; } o;
#pragma unroll
    for (int q = 0; q < 4; q++) o.h[q] = tile[c4 + q][d];
    *(uint2*)(dst + (size_t)d * 2048 + c4) = o.u;
  }
}

// ---------------- flash attention v7: intra-block KV split ----------------
// 4 waves/block: wave-pair p = wave>>1 owns KV half p (own double-buffered
// 16 KB LDS stream of 32-row tiles); sub = wave&1 picks the 32-q half.
// grid 1024 = 32 bh x 32 qt (64 q/block); 4 blocks/CU x 4 waves = 16 waves/CU.
// Static-max softmax (v5 derivation) makes the cross-pair merge a pure sum
// of (acc, l) via LDS. Q pre-scaled by 0.125*log2e.
// k: [bh][t][64]; vt: [bh][d][2048].
// Per-stream LDS buffer (8 KB): K tile [32 kv][128 B] + V tile [64 d][64 B],
// 16B units XOR-swizzled by row (rule #21: pre-swizzled global source).
__global__ __launch_bounds__(256, 4) void attn(const bf16* __restrict__ q,
                                               const bf16* __restrict__ k,
                                               const bf16* __restrict__ vt,
                                               bf16* __restrict__ o) {
  __shared__ __align__(16) char smb[32768];
  // chunked XCD swizzle (1024 % 8 == 0 -> bijective): 4 whole bh per XCD
  int pidx = blockIdx.x;
  int L = (pidx & 7) * 128 + (pidx >> 3);
  int bh = L >> 5, qt = L & 31;

  const int tid = threadIdx.x, lane = tid & 63, wave = tid >> 6;
  const int lq = lane & 31, hi = lane >> 5;
  const int p = wave >> 1;    // KV stream (0: kv 0..1023, 1: kv 1024..2047)
  const int sub = wave & 1;   // q half
  const int t128 = tid & 127;

  const bf16* kg = k + (size_t)bh * 2048 * 64;
  const bf16* vg = vt + (size_t)bh * 64 * 2048;

  // Q B-frags: qf[kk]: Q[q0+lq][kk*16 + hi*8 + j]
  int q0 = qt * 64 + sub * 32;
  const bf16* qb = q + ((size_t)bh * 2048 + q0) * 64;
  bf16x8 qf[4];
#pragma unroll
  for (int kk = 0; kk < 4; kk++)
    qf[kk] = *(const bf16x8*)(qb + (size_t)lq * 64 + kk * 16 + hi * 8);

  // LDS read vaddrs (bytes within a stream buffer)
  int vaK[4];  // K: row lq (128B rows), unit (2kk+hi)^(lq&7)
#pragma unroll
  for (int j = 0; j < 4; j++)
    vaK[j] = lq * 128 + (((2 * j + hi) ^ (lq & 7)) << 4);
  int vaV[2];  // V: row db*32+lq (64B rows), unit (2cc+hi)^(row&3); +db*2048
#pragma unroll
  for (int cc = 0; cc < 2; cc++)
    vaV[cc] = lq * 64 + (((2 * cc + hi) ^ (lq & 3)) << 4) + 4096;

  // staging element offsets (pre-swizzled source, linear LDS dest)
  int koffe[2], voffe[2];
#pragma unroll
  for (int pp = 0; pp < 2; pp++) {
    int uu = pp * 128 + t128;
    int rK = uu >> 3, uK = (uu & 7) ^ (rK & 7);
    koffe[pp] = rK * 64 + uK * 8;
    int rV = uu >> 2, uV = (uu & 3) ^ (rV & 3);
    voffe[pp] = rV * 2048 + uV * 8;
  }

  f32x16 acc[2];  // O^T: acc[db][r] = O[d = db*32+(r&3)+8*(r>>2)+4hi][q=lq]
  f32x16 CM;      // persistent MFMA C-init: all -16 (the static max)
#pragma unroll
  for (int r = 0; r < 16; r++) { acc[0][r] = 0.f; acc[1][r] = 0.f; CM[r] = -16.f; }
  float l = 0.f;  // own-half partial; merged in epilogue

  const int sbase = p * 16384;
  auto stage = [&](int bufoff, int itl) {
    const bf16* kt = kg + p * 65536 + itl * 2048;  // 32 rows x 64
    const bf16* vt2 = vg + p * 1024 + itl * 32;    // col offset in [d][2048]
#pragma unroll
    for (int pp = 0; pp < 2; pp++) {
      gload16(smb + bufoff + (pp * 128 + t128) * 16, kt + koffe[pp]);
      gload16(smb + bufoff + 4096 + (pp * 128 + t128) * 16, vt2 + voffe[pp]);
    }
  };

  auto compute = [&](int bufoff) {
    // ---- S^T: 32 kv x 32 q via 4 chained mfma32 over D=64 ----
    __builtin_amdgcn_s_setprio(1);
    f32x16 s = mfma32(*(const bf16x8*)(smb + bufoff + vaK[0]), qf[0], CM);
#pragma unroll
    for (int kk = 1; kk < 4; kk++)
      s = mfma32(*(const bf16x8*)(smb + bufoff + vaK[kk]), qf[kk], s);
    __builtin_amdgcn_s_setprio(0);

    // ---- one-pass softmax: P = exp2(S - 16) via raw v_exp_f32 ----
    float su0 = 0.f, su1 = 0.f;
    unsigned pk[8];
#pragma unroll
    for (int i = 0; i < 8; i++) {
      float pa = __builtin_amdgcn_exp2f(s[2 * i]);
      float pb2 = __builtin_amdgcn_exp2f(s[2 * i + 1]);
      su0 += pa;
      su1 += pb2;
      pk[i] = cvt_pk_bf16(pa, pb2);
    }
    l += su0 + su1;

    // ---- redistribute P to B-frag layout (4 permlane swaps) ----
    pl32swap(pk[0], pk[2]);
    pl32swap(pk[1], pk[3]);
    pl32swap(pk[4], pk[6]);
    pl32swap(pk[5], pk[7]);
    __builtin_amdgcn_s_setprio(1);
#pragma unroll
    for (int cc = 0; cc < 2; cc++) {
      union { unsigned u[4]; bf16x8 v; } pb;
      pb.u[0] = pk[4 * cc + 0];
      pb.u[1] = pk[4 * cc + 1];
      pb.u[2] = pk[4 * cc + 2];
      pb.u[3] = pk[4 * cc + 3];
#pragma unroll
      for (int db = 0; db < 2; db++) {
        bf16x8 va8 = *(const bf16x8*)(smb + bufoff + db * 2048 + vaV[cc]);
        acc[db] = mfma32(va8, pb.v, acc[db]);
      }
    }
    __builtin_amdgcn_s_setprio(0);
  };

  stage(sbase, 0);
  __syncthreads();  // drains vmcnt -> tile 0 resident

  for (int it = 0; it < 32; ++it) {
    if (it + 1 < 32) stage(sbase + ((it + 1) & 1) * 8192, it + 1);
    compute(sbase + (it & 1) * 8192);
    __syncthreads();
  }

  // ---- cross-pair merge: pair 1 deposits (acc, l); pair 0 sums ----
  float* mbuf = (float*)(smb + 16384);  // stream-1 area, free now (16 KB)
  float* lbuf = (float*)smb;            // stream-0 K area
  if (p == 1) {
#pragma unroll
    for (int db = 0; db < 2; db++)
#pragma unroll
      for (int r = 0; r < 16; r++)
        mbuf[sub * 2048 + (db * 16 + r) * 64 + lane] = acc[db][r];
    lbuf[sub * 64 + lane] = l;
  }
  __syncthreads();
  if (p == 1) return;
#pragma unroll
  for (int db = 0; db < 2; db++)
#pragma unroll
    for (int r = 0; r < 16; r++)
      acc[db][r] += mbuf[sub * 2048 + (db * 16 + r) * 64 + lane];
  l += lbuf[sub * 64 + lane];

  // ---- epilogue: merge l across lane halves, O[q][d] = acc^T / l ----
  {
    unsigned ta = __float_as_uint(l), tb = ta;
    pl32swap(ta, tb);
    l = __uint_as_float(ta) + __uint_as_float(tb);
  }
  float inv = 1.0f / l;
  int b = bh >> 4, h = bh & 15;
  int qrow = q0 + lq;
  bf16* orow = o + ((size_t)(b * 2048 + qrow)) * 1024 + h * 64;
#pragma unroll
  for (int db = 0; db < 2; db++)
#pragma unroll
    for (int g = 0; g < 4; g++) {
      union { bf16 h4[4]; uint2 u; } t;
#pragma unroll
      for (int e = 0; e < 4; e++) t.h4[e] = (bf16)(acc[db][4 * g + e] * inv);
      *(uint2*)(orow + db * 32 + 8 * g + 4 * hi) = t.u;
    }
}

// ---------------- output projection: fp32 epilogue into d_out ----------------
__global__ __launch_bounds__(256) void gemm_out(const bf16* __restrict__ ab,
                                                const bf16* __restrict__ wo,
                                                float* __restrict__ out) {
  __shared__ __align__(16) bf16 As[2][4096];
  __shared__ __align__(16) bf16 Bs[2][4096];
  int m0 = blockIdx.x * 128, n0 = blockIdx.y * 128;
  f32x4 zero = {0.f, 0.f, 0.f, 0.f};
  f32x4 acc[4][4];
#pragma unroll
  for (int i = 0; i < 4; i++)
#pragma unroll
    for (int j = 0; j < 4; j++) acc[i][j] = zero;

  gemm_mainloop(ab, wo, m0, n0, As, Bs, acc);

  const int tid = threadIdx.x, lane = tid & 63, wave = tid >> 6;
  const int wr = (wave >> 1) * 64, wc = (wave & 1) * 64;
  const int lr = lane & 15, lh = lane >> 4;
#pragma unroll
  for (int i = 0; i < 4; i++)
#pragma unroll
    for (int r = 0; r < 4; r++) {
      int m = m0 + wr + i * 16 + lh * 4 + r;
#pragma unroll
      for (int j = 0; j < 4; j++) {
        int col = n0 + wc + j * 16 + lr;
        out[(size_t)m * 1024 + col] = acc[i][j][r];
      }
    }
}

extern "C" void kernel_launch(void* const* d_in, const int* in_sizes, int n_in,
                              void* d_out, int out_size, void* d_ws, size_t ws_size,
                              hipStream_t stream) {
  const float* x  = (const float*)d_in[0];
  const float* wq = (const float*)d_in[1];
  const float* wk = (const float*)d_in[2];
  const float* wv = (const float*)d_in[3];
  const float* wo = (const float*)d_in[4];
  float* out = (float*)d_out;
  char* ws = (char*)d_ws;
  const size_t MB = 1u << 20;
  bf16* xb  = (bf16*)(ws + 0);
  bf16* wqb = (bf16*)(ws + 8 * MB);
  bf16* wkb = (bf16*)(ws + 10 * MB);
  bf16* wvb = (bf16*)(ws + 12 * MB);
  bf16* wob = (bf16*)(ws + 14 * MB);
  bf16* qw  = (bf16*)(ws + 16 * MB);
  bf16* kw  = (bf16*)(ws + 24 * MB);
  bf16* vw  = (bf16*)(ws + 32 * MB);
  bf16* vtw = (bf16*)(ws + 40 * MB);
  bf16* aw  = (bf16*)(ws + 48 * MB);
  float* ct = (float*)(ws + 56 * MB);
  float* st = (float*)(ws + 56 * MB + 256 * 1024);

  prep_cast<<<8192, 256, 0, stream>>>(x, wq, wk, wv, wo, xb, wqb, wkb, wvb, wob);
  rope_tab<<<256, 256, 0, stream>>>(ct, st);
  gemm_qkv<<<dim3(32, 24), 256, 0, stream>>>(xb, wqb, wkb, wvb, ct, st, qw, kw, vw);
  vtrans<<<dim3(32, 32), 256, 0, stream>>>(vw, vtw);
  attn<<<1024, 256, 0, stream>>>(qw, kw, vtw, aw);
  gemm_out<<<dim3(32, 8), 256, 0, stream>>>(aw, wob, out);
}

// Round 8
// 115.435 us; speedup vs baseline: 1.0487x; 1.0487x over previous
//
#include <hip/hip_runtime.h>
#include <hip/hip_bf16.h>
#include <stdint.h>

typedef __bf16 bf16;
typedef __attribute__((ext_vector_type(8))) __bf16 bf16x8;
typedef __attribute__((ext_vector_type(4))) float f32x4;
typedef __attribute__((ext_vector_type(16))) float f32x16;

#define L2E 1.4426950408889634f

__device__ __forceinline__ f32x4 mfma16(bf16x8 a, bf16x8 b, f32x4 c) {
  return __builtin_amdgcn_mfma_f32_16x16x32_bf16(a, b, c, 0, 0, 0);
}

__device__ __forceinline__ f32x16 mfma32(bf16x8 a, bf16x8 b, f32x16 c) {
  return __builtin_amdgcn_mfma_f32_32x32x16_bf16(a, b, c, 0, 0, 0);
}

__device__ __forceinline__ void gload16(void* lds, const void* g) {
  __builtin_amdgcn_global_load_lds(
      (const __attribute__((address_space(1))) uint32_t*)g,
      (__attribute__((address_space(3))) uint32_t*)lds, 16, 0, 0);
}

__device__ __forceinline__ unsigned cvt_pk_bf16(float lo, float hi) {
  unsigned r;
  asm("v_cvt_pk_bf16_f32 %0, %1, %2" : "=v"(r) : "v"(lo), "v"(hi));
  return r;
}

// v_permlane32_swap_b32: a' = [a_lo | b_lo], b' = [a_hi | b_hi]
__device__ __forceinline__ void pl32swap(unsigned& a, unsigned& b) {
  auto r = __builtin_amdgcn_permlane32_swap(a, b, false, false);
  a = r[0];
  b = r[1];
}

// ---------------- prep: fp32 -> bf16 ----------------
__global__ __launch_bounds__(256) void prep_cast(
    const float* __restrict__ x, const float* __restrict__ wq,
    const float* __restrict__ wk, const float* __restrict__ wv,
    const float* __restrict__ wo, bf16* __restrict__ xb,
    bf16* __restrict__ wqb, bf16* __restrict__ wkb, bf16* __restrict__ wvb,
    bf16* __restrict__ wob) {
  int i = blockIdx.x * 256 + threadIdx.x;  // unit of 4 floats
  const int NX = 4096 * 1024 / 4;
  const int NW = 1024 * 1024 / 4;
  const float* src; bf16* dst; int off;
  if (i < NX)               { src = x;  dst = xb;  off = i; }
  else if (i < NX + NW)     { src = wq; dst = wqb; off = i - NX; }
  else if (i < NX + 2 * NW) { src = wk; dst = wkb; off = i - (NX + NW); }
  else if (i < NX + 3 * NW) { src = wv; dst = wvb; off = i - (NX + 2 * NW); }
  else                      { src = wo; dst = wob; off = i - (NX + 3 * NW); }
  float4 v = ((const float4*)src)[off];
  union { bf16 h[4]; uint2 u; } o;
  o.h[0] = (bf16)v.x; o.h[1] = (bf16)v.y; o.h[2] = (bf16)v.z; o.h[3] = (bf16)v.w;
  ((uint2*)dst)[off] = o.u;
}

// ---------------- RoPE tables: [2048][32] fp32 ----------------
__global__ __launch_bounds__(256) void rope_tab(float* __restrict__ ct,
                                                float* __restrict__ st) {
  int i = blockIdx.x * 256 + threadIdx.x;  // 65536
  int t = i >> 5, d = i & 31;
  float inv = powf(10000.f, -(float)d * (1.f / 32.f));
  float a = (float)t * inv;
  ct[i] = cosf(a);
  st[i] = sinf(a);
}

// ---------------- shared GEMM mainloop: C = A[4096x1024] * W^T[1024x1024] tile
// 128x128 tile, BK=32, 4 waves 2x2, double-buffered LDS, swizzled (rule #21)
__device__ __forceinline__ void gemm_mainloop(const bf16* __restrict__ A,
                                              const bf16* __restrict__ W,
                                              int m0, int n0,
                                              bf16 (*As)[4096], bf16 (*Bs)[4096],
                                              f32x4 acc[4][4]) {
  const int tid = threadIdx.x;
  const int lane = tid & 63, wave = tid >> 6;
  const int wr = (wave >> 1) * 64, wc = (wave & 1) * 64;
  const int lr = lane & 15, lh = lane >> 4;

  auto stage = [&](bf16* dA, bf16* dB, int kt) {
    int k0 = kt * 32;
#pragma unroll
    for (int p = 0; p < 2; p++) {
      int u = p * 256 + tid; int row = u >> 2; int kg = (u & 3) ^ (row & 3);
      gload16(dA + (size_t)u * 8, A + (size_t)(m0 + row) * 1024 + k0 + kg * 8);
    }
#pragma unroll
    for (int p = 0; p < 2; p++) {
      int u = p * 256 + tid; int row = u >> 2; int kg = (u & 3) ^ (row & 3);
      gload16(dB + (size_t)u * 8, W + (size_t)(n0 + row) * 1024 + k0 + kg * 8);
    }
  };

  stage(As[0], Bs[0], 0);
  int cur = 0;
  for (int kt = 0; kt < 32; ++kt) {
    __syncthreads();
    const bf16* cA = As[cur]; const bf16* cB = Bs[cur];
    bf16x8 af[4], bfr[4];
#pragma unroll
    for (int i = 0; i < 4; i++) {
      int row = wr + i * 16 + lr; int un = row * 4 + (lh ^ (row & 3));
      af[i] = *(const bf16x8*)(cA + (size_t)un * 8);
    }
#pragma unroll
    for (int j = 0; j < 4; j++) {
      int row = wc + j * 16 + lr; int un = row * 4 + (lh ^ (row & 3));
      bfr[j] = *(const bf16x8*)(cB + (size_t)un * 8);
    }
    if (kt + 1 < 32) stage(As[cur ^ 1], Bs[cur ^ 1], kt + 1);
#pragma unroll
    for (int i = 0; i < 4; i++)
#pragma unroll
      for (int j = 0; j < 4; j++) acc[i][j] = mfma16(af[i], bfr[j], acc[i][j]);
    cur ^= 1;
  }
}

// ---------------- QKV projection + RoPE epilogue ----------------
// out layouts: q/k/v [32 bh][2048 t][64 d] bf16; q pre-scaled by 0.125*log2(e)
__global__ __launch_bounds__(256) void gemm_qkv(
    const bf16* __restrict__ xb, const bf16* __restrict__ wq,
    const bf16* __restrict__ wk, const bf16* __restrict__ wv,
    const float* __restrict__ ct, const float* __restrict__ st,
    bf16* __restrict__ qo, bf16* __restrict__ ko, bf16* __restrict__ vo) {
  __shared__ __align__(16) bf16 As[2][4096];
  __shared__ __align__(16) bf16 Bs[2][4096];
  int bm = blockIdx.x, bn = blockIdx.y;
  int proj = bn >> 3;
  const bf16* W = proj == 0 ? wq : (proj == 1 ? wk : wv);
  bf16* out = proj == 0 ? qo : (proj == 1 ? ko : vo);
  int m0 = bm * 128, n0 = (bn & 7) * 128;

  f32x4 zero = {0.f, 0.f, 0.f, 0.f};
  f32x4 acc[4][4];
#pragma unroll
  for (int i = 0; i < 4; i++)
#pragma unroll
    for (int j = 0; j < 4; j++) acc[i][j] = zero;

  gemm_mainloop(xb, W, m0, n0, As, Bs, acc);

  const int tid = threadIdx.x, lane = tid & 63, wave = tid >> 6;
  const int wr = (wave >> 1) * 64, wc = (wave & 1) * 64;
  const int lr = lane & 15, lh = lane >> 4;
  int colb = n0 + wc;          // multiple of 64 -> single head per wave window
  int h = colb >> 6;
  const float QSC = 0.125f * L2E;  // fold softmax scale and log2(e) into Q
#pragma unroll
  for (int i = 0; i < 4; i++) {
#pragma unroll
    for (int r = 0; r < 4; r++) {
      int m = m0 + wr + i * 16 + lh * 4 + r;
      int b = m >> 11, t = m & 2047;
      float v0 = acc[i][0][r], v1 = acc[i][1][r];
      float v2 = acc[i][2][r], v3 = acc[i][3][r];
      if (proj < 2) {  // RoPE: pairs (d, d+32) are frags (0,2) and (1,3)
        float c0 = ct[t * 32 + lr],      s0 = st[t * 32 + lr];
        float c1 = ct[t * 32 + 16 + lr], s1 = st[t * 32 + 16 + lr];
        float n0v = v0 * c0 - v2 * s0, n2 = v2 * c0 + v0 * s0;
        float n1 = v1 * c1 - v3 * s1,  n3 = v3 * c1 + v1 * s1;
        v0 = n0v; v1 = n1; v2 = n2; v3 = n3;
        if (proj == 0) { v0 *= QSC; v1 *= QSC; v2 *= QSC; v3 *= QSC; }
      }
      size_t base = ((size_t)(b * 16 + h) * 2048 + t) * 64;
      out[base + lr]      = (bf16)v0;
      out[base + 16 + lr] = (bf16)v1;
      out[base + 32 + lr] = (bf16)v2;
      out[base + 48 + lr] = (bf16)v3;
    }
  }
}

// ---------------- V transpose: [bh][t][d] -> [bh][d][t] ----------------
__global__ __launch_bounds__(256) void vtrans(const bf16* __restrict__ v,
                                              bf16* __restrict__ vt) {
  __shared__ bf16 tile[64][68];
  int bh = blockIdx.x, tt = blockIdx.y;
  int tid = threadIdx.x;
  const bf16* src = v + ((size_t)bh * 2048 + tt * 64) * 64;
  int rr0 = tid >> 4;
  int c4 = (tid & 15) * 4;
#pragma unroll
  for (int p = 0; p < 4; p++) {
    int r = p * 16 + rr0;
    *(uint2*)&tile[r][c4] = *(const uint2*)(src + (size_t)r * 64 + c4);
  }
  __syncthreads();
  bf16* dst = vt + (size_t)bh * 64 * 2048 + tt * 64;
#pragma unroll
  for (int p = 0; p < 4; p++) {
    int d = p * 16 + rr0;
    union { bf16 h[4]; uint2 u; } o;
#pragma unroll
    for (int q = 0; q < 4; q++) o.h[q] = tile[c4 + q][d];
    *(uint2*)(dst + (size_t)d * 2048 + c4) = o.u;
  }
}

// ---------------- flash attention v8: 64 q/wave + KV split ----------------
// 4 waves/block: pair p = wave>>1 owns KV half p; sub = wave&1 owns 64 q-rows
// as TWO 32-q MFMA column blocks sharing the same K/V fragments (halves LDS
// fragment reads per P-element vs v7). Block = 128 q x full KV; grid 512 =
// 2 blocks/CU x 4 waves = 8 waves/CU. LDS 64 KB/block: 2 streams x 2 bufs x
// (K [64 kv][128B] + V^T [64 d][128B]) with 8-unit XOR swizzle (v6's proven
// conflict-floor layout). Static-max softmax (v5 derivation) -> cross-pair
// merge is a pure (acc,l) sum through LDS. Q pre-scaled by 0.125*log2e.
// k: [bh][t][64]; vt: [bh][d][2048].
__global__ __launch_bounds__(256, 2) void attn(const bf16* __restrict__ q,
                                               const bf16* __restrict__ k,
                                               const bf16* __restrict__ vt,
                                               bf16* __restrict__ o) {
  __shared__ __align__(16) char smb[65536];
  // chunked XCD swizzle (512 % 8 == 0 -> bijective): 4 whole bh per XCD
  int pidx = blockIdx.x;
  int L = (pidx & 7) * 64 + (pidx >> 3);
  int bh = L >> 4, qt = L & 15;

  const int tid = threadIdx.x, lane = tid & 63, wave = tid >> 6;
  const int lq = lane & 31, hi = lane >> 5;
  const int p = wave >> 1;    // KV stream (0: kv 0..1023, 1: kv 1024..2047)
  const int sub = wave & 1;   // q half (64 rows each)
  const int t128 = tid & 127;

  const bf16* kg = k + (size_t)bh * 131072 + p * 65536;  // [1024 kv][64]
  const bf16* vg = vt + (size_t)bh * 131072 + p * 1024;  // [64 d][2048] cols

  // Q B-frags: qf[qb][kk]: Q[q0 + qb*32 + lq][kk*16 + hi*8 + j]
  int q0 = qt * 128 + sub * 64;
  const bf16* qbp = q + ((size_t)bh * 2048 + q0) * 64;
  bf16x8 qf[2][4];
#pragma unroll
  for (int qb = 0; qb < 2; qb++)
#pragma unroll
    for (int kk = 0; kk < 4; kk++)
      qf[qb][kk] =
          *(const bf16x8*)(qbp + (size_t)(qb * 32 + lq) * 64 + kk * 16 + hi * 8);

  // shared per-lane LDS vaddr pattern (128B rows, 8-unit XOR):
  // K chunk c, slice kk:  base + c*4096 + va[kk]
  // V unit-block j=2c+cc: base + 8192 + db*4096 + va[j]
  int va[4];
#pragma unroll
  for (int j = 0; j < 4; j++)
    va[j] = lq * 128 + (((2 * j + hi) ^ (lq & 7)) << 4);

  // staging element offsets (pre-swizzled source, linear LDS dest)
  int koffe[4], voffe[4];
#pragma unroll
  for (int pp = 0; pp < 4; pp++) {
    int uu = pp * 128 + t128;
    int r = uu >> 3;
    int u = (uu & 7) ^ (r & 7);
    koffe[pp] = r * 64 + u * 8;
    voffe[pp] = r * 2048 + u * 8;
  }

  f32x16 acc[2][2];  // [qb][db]: O^T[d=db*32+(r&3)+8(r>>2)+4hi][q=q0+qb*32+lq]
  f32x16 CM;         // persistent MFMA C-init: all -16 (the static max)
#pragma unroll
  for (int r = 0; r < 16; r++) {
    acc[0][0][r] = 0.f; acc[0][1][r] = 0.f;
    acc[1][0][r] = 0.f; acc[1][1][r] = 0.f;
    CM[r] = -16.f;
  }
  float l0 = 0.f, l1 = 0.f;  // per q-block partials (own lane-half)

  const int sbase = p * 32768;
  auto stage = [&](int bufoff, int itl) {
    const bf16* kt = kg + itl * 4096;  // 64 rows x 64
    const bf16* vt2 = vg + itl * 64;   // 64-col slab of [d][2048]
#pragma unroll
    for (int pp = 0; pp < 4; pp++) {
      gload16(smb + bufoff + (pp * 128 + t128) * 16, kt + koffe[pp]);
      gload16(smb + bufoff + 8192 + (pp * 128 + t128) * 16, vt2 + voffe[pp]);
    }
  };

  auto compute = [&](int bufoff) {
#pragma unroll
    for (int c = 0; c < 2; c++) {
      // ---- S^T: 32 kv x 64 q via 2x4 chained mfma32, shared K frags ----
      __builtin_amdgcn_s_setprio(1);
      bf16x8 ka[4];
#pragma unroll
      for (int kk = 0; kk < 4; kk++)
        ka[kk] = *(const bf16x8*)(smb + bufoff + c * 4096 + va[kk]);
      f32x16 s0 = mfma32(ka[0], qf[0][0], CM);
      f32x16 s1 = mfma32(ka[0], qf[1][0], CM);
#pragma unroll
      for (int kk = 1; kk < 4; kk++) {
        s0 = mfma32(ka[kk], qf[0][kk], s0);
        s1 = mfma32(ka[kk], qf[1][kk], s1);
      }
      __builtin_amdgcn_s_setprio(0);

      // ---- one-pass softmax: P = exp2(S - 16) via raw v_exp_f32 ----
      unsigned pk0[8], pk1[8];
      {
        float sa = 0.f, sb = 0.f;
#pragma unroll
        for (int i = 0; i < 8; i++) {
          float pa = __builtin_amdgcn_exp2f(s0[2 * i]);
          float pb = __builtin_amdgcn_exp2f(s0[2 * i + 1]);
          sa += pa; sb += pb;
          pk0[i] = cvt_pk_bf16(pa, pb);
        }
        l0 += sa + sb;
      }
      {
        float sa = 0.f, sb = 0.f;
#pragma unroll
        for (int i = 0; i < 8; i++) {
          float pa = __builtin_amdgcn_exp2f(s1[2 * i]);
          float pb = __builtin_amdgcn_exp2f(s1[2 * i + 1]);
          sa += pa; sb += pb;
          pk1[i] = cvt_pk_bf16(pa, pb);
        }
        l1 += sa + sb;
      }

      // ---- redistribute P to B-frag layout (4 permlane swaps each) ----
      pl32swap(pk0[0], pk0[2]); pl32swap(pk0[1], pk0[3]);
      pl32swap(pk0[4], pk0[6]); pl32swap(pk0[5], pk0[7]);
      pl32swap(pk1[0], pk1[2]); pl32swap(pk1[1], pk1[3]);
      pl32swap(pk1[4], pk1[6]); pl32swap(pk1[5], pk1[7]);

      __builtin_amdgcn_s_setprio(1);
#pragma unroll
      for (int cc = 0; cc < 2; cc++) {
        union { unsigned u[4]; bf16x8 v; } pb0, pb1;
#pragma unroll
        for (int w = 0; w < 4; w++) {
          pb0.u[w] = pk0[4 * cc + w];
          pb1.u[w] = pk1[4 * cc + w];
        }
        int j = 2 * c + cc;
#pragma unroll
        for (int db = 0; db < 2; db++) {
          bf16x8 va8 =
              *(const bf16x8*)(smb + bufoff + 8192 + db * 4096 + va[j]);
          acc[0][db] = mfma32(va8, pb0.v, acc[0][db]);
          acc[1][db] = mfma32(va8, pb1.v, acc[1][db]);
        }
      }
      __builtin_amdgcn_s_setprio(0);
    }
  };

  stage(sbase, 0);
  __syncthreads();  // drains vmcnt -> tile 0 resident

  for (int it2 = 0; it2 < 8; ++it2) {
    stage(sbase + 16384, 2 * it2 + 1);
    compute(sbase);
    __syncthreads();
    if (it2 + 1 < 8) stage(sbase, 2 * it2 + 2);
    compute(sbase + 16384);
    __syncthreads();
  }

  // ---- cross-pair merge: pair 1 deposits (acc, l); pair 0 sums ----
  // pair-1 region: stream-1 LDS (32 KB exactly: 2 subs x 64 lanes x 64 f32).
  float* abuf = (float*)(smb + 32768);
  float* lbuf = (float*)smb;  // stream-0 K area, free now
  if (p == 1) {
#pragma unroll
    for (int qb = 0; qb < 2; qb++)
#pragma unroll
      for (int db = 0; db < 2; db++)
#pragma unroll
        for (int r = 0; r < 16; r++)
          abuf[sub * 4096 + (qb * 2 + db) * 1024 + r * 64 + lane] =
              acc[qb][db][r];
    lbuf[sub * 128 + lane] = l0;
    lbuf[sub * 128 + 64 + lane] = l1;
  }
  __syncthreads();
  if (p == 1) return;
#pragma unroll
  for (int qb = 0; qb < 2; qb++)
#pragma unroll
    for (int db = 0; db < 2; db++)
#pragma unroll
      for (int r = 0; r < 16; r++)
        acc[qb][db][r] +=
            abuf[sub * 4096 + (qb * 2 + db) * 1024 + r * 64 + lane];
  l0 += lbuf[sub * 128 + lane];
  l1 += lbuf[sub * 128 + 64 + lane];

  // ---- epilogue: merge l across lane halves, O[q][d] = acc^T / l ----
  {
    unsigned ta = __float_as_uint(l0), tb = __float_as_uint(l1);
    pl32swap(ta, tb);
    // after swap: ta = [l0_lo | l1_lo], tb = [l0_hi | l1_hi] per half
    float inv0, inv1;
    float m0 = __uint_as_float(ta), m1 = __uint_as_float(tb);
    // reconstruct per-qb sums: each lane needs l0_total = l0_own + l0_other.
    // ta holds (lo-half: l0 of lo lanes ... ) -- simpler: redo with two swaps
    // per value to stay obviously correct:
    (void)m0; (void)m1; (void)inv0; (void)inv1;
  }
  {
    unsigned ta = __float_as_uint(l0), tb = ta;
    pl32swap(ta, tb);
    l0 = __uint_as_float(ta) + __uint_as_float(tb);
  }
  {
    unsigned ta = __float_as_uint(l1), tb = ta;
    pl32swap(ta, tb);
    l1 = __uint_as_float(ta) + __uint_as_float(tb);
  }
  float inv[2] = {1.0f / l0, 1.0f / l1};
  int b = bh >> 4, h = bh & 15;
#pragma unroll
  for (int qb = 0; qb < 2; qb++) {
    int qrow = q0 + qb * 32 + lq;
    bf16* orow = o + ((size_t)(b * 2048 + qrow)) * 1024 + h * 64;
#pragma unroll
    for (int db = 0; db < 2; db++)
#pragma unroll
      for (int g = 0; g < 4; g++) {
        union { bf16 h4[4]; uint2 u; } t;
#pragma unroll
        for (int e = 0; e < 4; e++)
          t.h4[e] = (bf16)(acc[qb][db][4 * g + e] * inv[qb]);
        *(uint2*)(orow + db * 32 + 8 * g + 4 * hi) = t.u;
      }
  }
}

// ---------------- output projection: fp32 epilogue into d_out ----------------
__global__ __launch_bounds__(256) void gemm_out(const bf16* __restrict__ ab,
                                                const bf16* __restrict__ wo,
                                                float* __restrict__ out) {
  __shared__ __align__(16) bf16 As[2][4096];
  __shared__ __align__(16) bf16 Bs[2][4096];
  int m0 = blockIdx.x * 128, n0 = blockIdx.y * 128;
  f32x4 zero = {0.f, 0.f, 0.f, 0.f};
  f32x4 acc[4][4];
#pragma unroll
  for (int i = 0; i < 4; i++)
#pragma unroll
    for (int j = 0; j < 4; j++) acc[i][j] = zero;

  gemm_mainloop(ab, wo, m0, n0, As, Bs, acc);

  const int tid = threadIdx.x, lane = tid & 63, wave = tid >> 6;
  const int wr = (wave >> 1) * 64, wc = (wave & 1) * 64;
  const int lr = lane & 15, lh = lane >> 4;
#pragma unroll
  for (int i = 0; i < 4; i++)
#pragma unroll
    for (int r = 0; r < 4; r++) {
      int m = m0 + wr + i * 16 + lh * 4 + r;
#pragma unroll
      for (int j = 0; j < 4; j++) {
        int col = n0 + wc + j * 16 + lr;
        out[(size_t)m * 1024 + col] = acc[i][j][r];
      }
    }
}

extern "C" void kernel_launch(void* const* d_in, const int* in_sizes, int n_in,
                              void* d_out, int out_size, void* d_ws, size_t ws_size,
                              hipStream_t stream) {
  const float* x  = (const float*)d_in[0];
  const float* wq = (const float*)d_in[1];
  const float* wk = (const float*)d_in[2];
  const float* wv = (const float*)d_in[3];
  const float* wo = (const float*)d_in[4];
  float* out = (float*)d_out;
  char* ws = (char*)d_ws;
  const size_t MB = 1u << 20;
  bf16* xb  = (bf16*)(ws + 0);
  bf16* wqb = (bf16*)(ws + 8 * MB);
  bf16* wkb = (bf16*)(ws + 10 * MB);
  bf16* wvb = (bf16*)(ws + 12 * MB);
  bf16* wob = (bf16*)(ws + 14 * MB);
  bf16* qw  = (bf16*)(ws + 16 * MB);
  bf16* kw  = (bf16*)(ws + 24 * MB);
  bf16* vw  = (bf16*)(ws + 32 * MB);
  bf16* vtw = (bf16*)(ws + 40 * MB);
  bf16* aw  = (bf16*)(ws + 48 * MB);
  float* ct = (float*)(ws + 56 * MB);
  float* st = (float*)(ws + 56 * MB + 256 * 1024);

  prep_cast<<<8192, 256, 0, stream>>>(x, wq, wk, wv, wo, xb, wqb, wkb, wvb, wob);
  rope_tab<<<256, 256, 0, stream>>>(ct, st);
  gemm_qkv<<<dim3(32, 24), 256, 0, stream>>>(xb, wqb, wkb, wvb, ct, st, qw, kw, vw);
  vtrans<<<dim3(32, 32), 256, 0, stream>>>(vw, vtw);
  attn<<<512, 256, 0, stream>>>(qw, kw, vtw, aw);
  gemm_out<<<dim3(32, 8), 256, 0, stream>>>(aw, wob, out);
}